// Round 1
// baseline (524.383 us; speedup 1.0000x reference)
//
#include <hip/hip_runtime.h>

#define TT 8192
#define DIN 512

// ---------------- Kernel 1: q,k,v = x @ {Wq,Wk,Wv} (f32) ----------------
__global__ __launch_bounds__(256) void proj_kernel(
    const float* __restrict__ x,
    const float* __restrict__ Wq, const float* __restrict__ Wk, const float* __restrict__ Wv,
    float* __restrict__ q, float* __restrict__ k, float* __restrict__ v)
{
    __shared__ float xs[64][33];   // 64 rows x 32 k-chunk, padded
    __shared__ float wsm[32][65];  // 32 k x 64 cols, padded

    const float* W = blockIdx.y == 0 ? Wq : (blockIdx.y == 1 ? Wk : Wv);
    float* o       = blockIdx.y == 0 ? q  : (blockIdx.y == 1 ? k  : v);

    const int rowBase = blockIdx.x * 64;
    const int tid = threadIdx.x;
    const int tx = tid & 15, ty = tid >> 4;   // 16x16 threads, 4x4 micro-tile each

    float acc[4][4] = {{0.f}};

    for (int kk = 0; kk < DIN; kk += 32) {
        for (int idx = tid; idx < 64 * 32; idx += 256) {
            int r = idx >> 5, c = idx & 31;
            xs[r][c] = x[(size_t)(rowBase + r) * DIN + kk + c];
        }
        for (int idx = tid; idx < 32 * 64; idx += 256) {
            int r = idx >> 6, c = idx & 63;
            wsm[r][c] = W[(size_t)(kk + r) * 64 + c];
        }
        __syncthreads();
        #pragma unroll
        for (int p = 0; p < 32; ++p) {
            float a[4], b[4];
            #pragma unroll
            for (int r = 0; r < 4; ++r) a[r] = xs[ty * 4 + r][p];
            #pragma unroll
            for (int c = 0; c < 4; ++c) b[c] = wsm[p][tx * 4 + c];
            #pragma unroll
            for (int r = 0; r < 4; ++r)
                #pragma unroll
                for (int c = 0; c < 4; ++c)
                    acc[r][c] += a[r] * b[c];
        }
        __syncthreads();
    }
    #pragma unroll
    for (int r = 0; r < 4; ++r)
        #pragma unroll
        for (int c = 0; c < 4; ++c)
            o[(size_t)(rowBase + ty * 4 + r) * 64 + tx * 4 + c] = acc[r][c];
}

// ---------------- Kernel 2: out[t,:] = sum_{s<=t} (q_t . k_s) * l[t,s] * v[s,:] ----------------
#define TM 32
#define TS 32
#define SCHUNK 1024

__global__ __launch_bounds__(256) void attn_kernel(
    const float* __restrict__ q, const float* __restrict__ k, const float* __restrict__ v,
    const float* __restrict__ l, float* __restrict__ out)
{
    __shared__ float q_s[TM][65];
    __shared__ float k_s[TS][65];
    __shared__ float v_s[TS][65];
    __shared__ float S_s[TM][33];

    const int t0 = blockIdx.x * TM;
    const int sStart = blockIdx.y * SCHUNK;
    if (sStart >= t0 + TM) return;                 // chunk entirely above diagonal
    const int sEnd = min(sStart + SCHUNK, t0 + TM); // s <= t bound (tile-aligned)

    const int tid = threadIdx.x;
    const int i  = tid >> 3;   // output row within tile, 0..31
    const int dg = tid & 7;    // output col group, 8 floats each

    // stage q tile (32x64)
    for (int idx = tid; idx < TM * 64; idx += 256) {
        int r = idx >> 6, c = idx & 63;
        q_s[r][c] = q[(size_t)(t0 + r) * 64 + c];
    }

    float acc[8];
    #pragma unroll
    for (int z = 0; z < 8; ++z) acc[z] = 0.f;

    __syncthreads();

    for (int s0 = sStart; s0 < sEnd; s0 += TS) {
        // stage k,v tiles (32x64 each)
        for (int idx = tid; idx < TS * 64; idx += 256) {
            int r = idx >> 6, c = idx & 63;
            k_s[r][c] = k[(size_t)(s0 + r) * 64 + c];
            v_s[r][c] = v[(size_t)(s0 + r) * 64 + c];
        }
        __syncthreads();

        // phase 1: S[i][j] = (q_i . k_j) * l[t0+i, s0+j], masked to s<=t
        {
            const int si = tid >> 3;
            const int j0 = (tid & 7) * 4;
            float d0 = 0.f, d1 = 0.f, d2 = 0.f, d3 = 0.f;
            #pragma unroll
            for (int p = 0; p < 64; ++p) {
                float a = q_s[si][p];
                d0 += a * k_s[j0 + 0][p];
                d1 += a * k_s[j0 + 1][p];
                d2 += a * k_s[j0 + 2][p];
                d3 += a * k_s[j0 + 3][p];
            }
            const int trow = t0 + si;
            const float4 lv = *reinterpret_cast<const float4*>(
                l + (size_t)trow * TT + s0 + j0);
            S_s[si][j0 + 0] = (s0 + j0 + 0 <= trow) ? d0 * lv.x : 0.f;
            S_s[si][j0 + 1] = (s0 + j0 + 1 <= trow) ? d1 * lv.y : 0.f;
            S_s[si][j0 + 2] = (s0 + j0 + 2 <= trow) ? d2 * lv.z : 0.f;
            S_s[si][j0 + 3] = (s0 + j0 + 3 <= trow) ? d3 * lv.w : 0.f;
        }
        __syncthreads();

        // phase 2: acc[d] += sum_j S[i][j] * v[j][d]
        #pragma unroll 8
        for (int j = 0; j < TS; ++j) {
            float s = S_s[i][j];
            #pragma unroll
            for (int z = 0; z < 8; ++z)
                acc[z] += s * v_s[j][dg * 8 + z];
        }
        __syncthreads();
    }

    #pragma unroll
    for (int z = 0; z < 8; ++z)
        atomicAdd(&out[(size_t)(t0 + i) * 64 + dg * 8 + z], acc[z]);
}

extern "C" void kernel_launch(void* const* d_in, const int* in_sizes, int n_in,
                              void* d_out, int out_size, void* d_ws, size_t ws_size,
                              hipStream_t stream) {
    const float* x  = (const float*)d_in[0];
    const float* Wq = (const float*)d_in[1];
    const float* Wk = (const float*)d_in[2];
    const float* Wv = (const float*)d_in[3];
    const float* l  = (const float*)d_in[4];
    float* out = (float*)d_out;

    // workspace: q,k,v f32 [TT x 64] each = 6 MB total
    float* q = (float*)d_ws;
    float* k = q + (size_t)TT * 64;
    float* v = k + (size_t)TT * 64;

    hipMemsetAsync(d_out, 0, (size_t)out_size * sizeof(float), stream);
    proj_kernel<<<dim3(TT / 64, 3), 256, 0, stream>>>(x, Wq, Wk, Wv, q, k, v);
    attn_kernel<<<dim3(TT / TM, TT / SCHUNK), 256, 0, stream>>>(q, k, v, l, out);
}

// Round 2
// 126.274 us; speedup vs baseline: 4.1527x; 4.1527x over previous
//
#include <hip/hip_runtime.h>
#include <hip/hip_bf16.h>

#define TT 8192
#define DIN 512
#define DQK 64

typedef __attribute__((ext_vector_type(8))) short short8;
typedef __attribute__((ext_vector_type(4))) float f32x4;

// ---------------- Kernel 1: q,k = bf16(x@W), vt = bf16((x@Wv)^T) ----------------
__global__ __launch_bounds__(256) void proj_kernel(
    const float* __restrict__ x,
    const float* __restrict__ Wq, const float* __restrict__ Wk, const float* __restrict__ Wv,
    __hip_bfloat16* __restrict__ qb, __hip_bfloat16* __restrict__ kb,
    __hip_bfloat16* __restrict__ vt)
{
    __shared__ float xs[64][33];
    __shared__ float wsm[32][65];

    const float* W = blockIdx.y == 0 ? Wq : (blockIdx.y == 1 ? Wk : Wv);

    const int rowBase = blockIdx.x * 64;
    const int tid = threadIdx.x;
    const int tx = tid & 15, ty = tid >> 4;

    float acc[4][4] = {{0.f}};

    for (int kk = 0; kk < DIN; kk += 32) {
        for (int idx = tid; idx < 64 * 32; idx += 256) {
            int r = idx >> 5, c = idx & 31;
            xs[r][c] = x[(size_t)(rowBase + r) * DIN + kk + c];
        }
        for (int idx = tid; idx < 32 * 64; idx += 256) {
            int r = idx >> 6, c = idx & 63;
            wsm[r][c] = W[(size_t)(kk + r) * 64 + c];
        }
        __syncthreads();
        #pragma unroll
        for (int p = 0; p < 32; ++p) {
            float a[4], b[4];
            #pragma unroll
            for (int r = 0; r < 4; ++r) a[r] = xs[ty * 4 + r][p];
            #pragma unroll
            for (int c = 0; c < 4; ++c) b[c] = wsm[p][tx * 4 + c];
            #pragma unroll
            for (int r = 0; r < 4; ++r)
                #pragma unroll
                for (int c = 0; c < 4; ++c)
                    acc[r][c] += a[r] * b[c];
        }
        __syncthreads();
    }

    if (blockIdx.y < 2) {
        __hip_bfloat16* o = blockIdx.y == 0 ? qb : kb;
        #pragma unroll
        for (int r = 0; r < 4; ++r)
            #pragma unroll
            for (int c = 0; c < 4; ++c)
                o[(size_t)(rowBase + ty * 4 + r) * DQK + tx * 4 + c] =
                    __float2bfloat16(acc[r][c]);
    } else {
        // transposed store: vt[d][t]
        #pragma unroll
        for (int r = 0; r < 4; ++r)
            #pragma unroll
            for (int c = 0; c < 4; ++c)
                vt[(size_t)(tx * 4 + c) * TT + rowBase + ty * 4 + r] =
                    __float2bfloat16(acc[r][c]);
    }
}

// ---------------- Kernel 2: MFMA attention-like core ----------------
#define TM 64        // t rows per block (4 waves x 16)
#define TS 64        // s per step
#define SCHUNK 512   // s range per block (grid.y)
#define LP 72        // padded LDS row stride in shorts (144 B)

__global__ __launch_bounds__(256) void attn_kernel(
    const __hip_bfloat16* __restrict__ qb,
    const __hip_bfloat16* __restrict__ kb,
    const __hip_bfloat16* __restrict__ vt,
    const float* __restrict__ l,
    float* __restrict__ out)
{
    __shared__ short K_lds[TS][LP];      // K[s][k]
    __shared__ short V_lds[DQK][LP];     // Vt[d][s_local]
    __shared__ short S_lds[4][16][LP];   // per-wave S[t_loc][s_local], bf16

    const int t0 = blockIdx.x * TM;
    const int sStart = blockIdx.y * SCHUNK;
    if (sStart >= t0 + TM) return;
    const int sEnd = min(sStart + SCHUNK, t0 + TM);

    const int tid = threadIdx.x;
    const int lane = tid & 63;
    const int w = tid >> 6;
    const int lo = lane & 15;
    const int hi = lane >> 4;

    // Q fragments: A[row=lo][k = hi*8 + j], two k-halves
    short8 qfrag0, qfrag1;
    {
        const short* qp = (const short*)(qb + (size_t)(t0 + w * 16 + lo) * DQK);
        qfrag0 = *(const short8*)(qp + 0 * 32 + hi * 8);
        qfrag1 = *(const short8*)(qp + 1 * 32 + hi * 8);
    }

    f32x4 acc_o[4];
    #pragma unroll
    for (int i = 0; i < 4; ++i) acc_o[i] = (f32x4){0.f, 0.f, 0.f, 0.f};

    for (int s0 = sStart; s0 < sEnd; s0 += TS) {
        // stage K tile and Vt tile (each 64 x 64 bf16)
        {
            const int c8 = (tid & 7) * 8;
            #pragma unroll
            for (int it = 0; it < 2; ++it) {
                const int row = (tid >> 3) + it * 32;
                *(short8*)&K_lds[row][c8] =
                    *(const short8*)((const short*)kb + (size_t)(s0 + row) * DQK + c8);
                *(short8*)&V_lds[row][c8] =
                    *(const short8*)((const short*)vt + (size_t)row * TT + s0 + c8);
            }
        }
        __syncthreads();

        // QK^T -> *l -> mask -> bf16 -> S_lds
        #pragma unroll
        for (int sub = 0; sub < 4; ++sub) {
            f32x4 acc = (f32x4){0.f, 0.f, 0.f, 0.f};
            short8 b0 = *(const short8*)&K_lds[sub * 16 + lo][0 * 32 + hi * 8];
            short8 b1 = *(const short8*)&K_lds[sub * 16 + lo][1 * 32 + hi * 8];
            acc = __builtin_amdgcn_mfma_f32_16x16x32_bf16(qfrag0, b0, acc, 0, 0, 0);
            acc = __builtin_amdgcn_mfma_f32_16x16x32_bf16(qfrag1, b1, acc, 0, 0, 0);
            const int s_glob = s0 + sub * 16 + lo;   // C col = s
            #pragma unroll
            for (int r = 0; r < 4; ++r) {
                const int tg = t0 + w * 16 + hi * 4 + r;   // C row = t
                float lv = l[(size_t)tg * TT + s_glob];
                float sv = (s_glob <= tg) ? acc[r] * lv : 0.f;
                __hip_bfloat16 h = __float2bfloat16(sv);
                S_lds[w][hi * 4 + r][sub * 16 + lo] = *(short*)&h;
            }
        }
        __syncthreads();

        // PV: O[16t x 64d] += S[16t x 64s] * V[64s x 64d]
        short8 a0 = *(const short8*)&S_lds[w][lo][0 * 32 + hi * 8];
        short8 a1 = *(const short8*)&S_lds[w][lo][1 * 32 + hi * 8];
        #pragma unroll
        for (int ds = 0; ds < 4; ++ds) {
            short8 b0 = *(const short8*)&V_lds[ds * 16 + lo][0 * 32 + hi * 8];
            short8 b1 = *(const short8*)&V_lds[ds * 16 + lo][1 * 32 + hi * 8];
            acc_o[ds] = __builtin_amdgcn_mfma_f32_16x16x32_bf16(a0, b0, acc_o[ds], 0, 0, 0);
            acc_o[ds] = __builtin_amdgcn_mfma_f32_16x16x32_bf16(a1, b1, acc_o[ds], 0, 0, 0);
        }
        __syncthreads();
    }

    // epilogue: accumulate partials
    #pragma unroll
    for (int ds = 0; ds < 4; ++ds) {
        #pragma unroll
        for (int r = 0; r < 4; ++r) {
            const int tg = t0 + w * 16 + hi * 4 + r;
            atomicAdd(&out[(size_t)tg * DQK + ds * 16 + lo], acc_o[ds][r]);
        }
    }
}

extern "C" void kernel_launch(void* const* d_in, const int* in_sizes, int n_in,
                              void* d_out, int out_size, void* d_ws, size_t ws_size,
                              hipStream_t stream) {
    const float* x  = (const float*)d_in[0];
    const float* Wq = (const float*)d_in[1];
    const float* Wk = (const float*)d_in[2];
    const float* Wv = (const float*)d_in[3];
    const float* l  = (const float*)d_in[4];
    float* out = (float*)d_out;

    __hip_bfloat16* qb = (__hip_bfloat16*)d_ws;
    __hip_bfloat16* kb = qb + (size_t)TT * DQK;
    __hip_bfloat16* vt = kb + (size_t)TT * DQK;

    hipMemsetAsync(d_out, 0, (size_t)out_size * sizeof(float), stream);
    proj_kernel<<<dim3(TT / 64, 3), 256, 0, stream>>>(x, Wq, Wk, Wv, qb, kb, vt);
    attn_kernel<<<dim3(TT / TM, TT / SCHUNK), 256, 0, stream>>>(qb, kb, vt, l, out);
}

// Round 3
// 77.821 us; speedup vs baseline: 6.7384x; 1.6226x over previous
//
#include <hip/hip_runtime.h>
#include <hip/hip_bf16.h>

#define TT 8192
#define DIN 512
#define DQK 64

typedef __attribute__((ext_vector_type(8))) short short8;
typedef __attribute__((ext_vector_type(4))) float f32x4;

// ---------------- zero kernel (replaces memset; keeps profile clean) ----------------
__global__ __launch_bounds__(256) void zero_kernel(float* __restrict__ out, int n4)
{
    int i = blockIdx.x * 256 + threadIdx.x;
    if (i < n4) ((f32x4*)out)[i] = (f32x4){0.f, 0.f, 0.f, 0.f};
}

// ---------------- Kernel 1: MFMA projections. q,k [T][64] bf16; vt [64][T] bf16 ----------------
#define PP 72

__global__ __launch_bounds__(256) void proj_kernel(
    const float* __restrict__ x,
    const float* __restrict__ Wq, const float* __restrict__ Wk, const float* __restrict__ Wv,
    __hip_bfloat16* __restrict__ qb, __hip_bfloat16* __restrict__ kb,
    __hip_bfloat16* __restrict__ vt)
{
    __shared__ short xb[64][PP];        // x tile [row][k]
    __shared__ short wb[3][64][PP];     // W^T tiles [matrix][col][k]

    const int rowBase = blockIdx.x * 64;
    const int tid = threadIdx.x;
    const int lane = tid & 63;
    const int w = tid >> 6;
    const int lo = lane & 15, hi = lane >> 4;

    f32x4 acc[3][4];
    #pragma unroll
    for (int m = 0; m < 3; ++m)
        #pragma unroll
        for (int cf = 0; cf < 4; ++cf) acc[m][cf] = (f32x4){0.f, 0.f, 0.f, 0.f};

    for (int kk = 0; kk < DIN; kk += 64) {
        // stage x 64x64 -> bf16
        {
            const int r = tid >> 2;
            const int c0 = (tid & 3) * 16;
            const float* xp = x + (size_t)(rowBase + r) * DIN + kk + c0;
            short tmp[16];
            #pragma unroll
            for (int j = 0; j < 16; ++j) {
                __hip_bfloat16 h = __float2bfloat16(xp[j]);
                tmp[j] = *(short*)&h;
            }
            *(short8*)&xb[r][c0]     = *(short8*)&tmp[0];
            *(short8*)&xb[r][c0 + 8] = *(short8*)&tmp[8];
        }
        // stage W^T 3x(64x64) -> bf16 (transposed scatter)
        {
            const int kr = tid >> 2;
            const int c0 = (tid & 3) * 16;
            #pragma unroll
            for (int m = 0; m < 3; ++m) {
                const float* Wm = (m == 0 ? Wq : (m == 1 ? Wk : Wv));
                const float* wp = Wm + (size_t)(kk + kr) * DQK + c0;
                #pragma unroll
                for (int j = 0; j < 16; ++j) {
                    __hip_bfloat16 h = __float2bfloat16(wp[j]);
                    wb[m][c0 + j][kr] = *(short*)&h;
                }
            }
        }
        __syncthreads();

        short8 a0 = *(short8*)&xb[w * 16 + lo][hi * 8];
        short8 a1 = *(short8*)&xb[w * 16 + lo][32 + hi * 8];
        #pragma unroll
        for (int m = 0; m < 3; ++m) {
            #pragma unroll
            for (int cf = 0; cf < 4; ++cf) {
                short8 b0 = *(short8*)&wb[m][cf * 16 + lo][hi * 8];
                short8 b1 = *(short8*)&wb[m][cf * 16 + lo][32 + hi * 8];
                acc[m][cf] = __builtin_amdgcn_mfma_f32_16x16x32_bf16(a0, b0, acc[m][cf], 0, 0, 0);
                acc[m][cf] = __builtin_amdgcn_mfma_f32_16x16x32_bf16(a1, b1, acc[m][cf], 0, 0, 0);
            }
        }
        __syncthreads();
    }

    // epilogue: C row = t (hi*4+r), col = d (cf*16+lo)
    #pragma unroll
    for (int cf = 0; cf < 4; ++cf) {
        #pragma unroll
        for (int r = 0; r < 4; ++r) {
            const int tg = rowBase + w * 16 + hi * 4 + r;
            const int d  = cf * 16 + lo;
            __hip_bfloat16 hq = __float2bfloat16(acc[0][cf][r]);
            __hip_bfloat16 hk = __float2bfloat16(acc[1][cf][r]);
            __hip_bfloat16 hv = __float2bfloat16(acc[2][cf][r]);
            qb[(size_t)tg * DQK + d] = hq;
            kb[(size_t)tg * DQK + d] = hk;
            vt[(size_t)d * TT + tg]  = hv;
        }
    }
}

// ---------------- Kernel 2: MFMA triangular core ----------------
#define TM 128       // t rows per block (8 waves x 16)
#define TS 64        // s per step
#define SCHUNK 256   // s range per block (grid.y)
#define LP 72        // padded LDS row stride in shorts (144 B)

__global__ __launch_bounds__(512) void attn_kernel(
    const __hip_bfloat16* __restrict__ qb,
    const __hip_bfloat16* __restrict__ kb,
    const __hip_bfloat16* __restrict__ vt,
    const float* __restrict__ l,
    float* __restrict__ out)
{
    __shared__ short K_lds[TS][LP];      // K[s][k]
    __shared__ short V_lds[DQK][LP];     // Vt[d][s_local]
    __shared__ short S_lds[8][16][LP];   // per-wave S[t_loc][s_local], bf16

    const int t0 = blockIdx.x * TM;
    const int sStart = blockIdx.y * SCHUNK;
    if (sStart >= t0 + TM) return;
    const int sEnd = min(sStart + SCHUNK, t0 + TM);

    const int tid = threadIdx.x;
    const int lane = tid & 63;
    const int w = tid >> 6;              // 0..7
    const int lo = lane & 15, hi = lane >> 4;
    const int trow = t0 + w * 16;        // wave's 16-row slab base

    short8 qf0, qf1;
    {
        const short* qp = (const short*)qb + (size_t)(trow + lo) * DQK;
        qf0 = *(const short8*)(qp + hi * 8);
        qf1 = *(const short8*)(qp + 32 + hi * 8);
    }

    f32x4 acc_o[4];
    #pragma unroll
    for (int i = 0; i < 4; ++i) acc_o[i] = (f32x4){0.f, 0.f, 0.f, 0.f};

    for (int s0 = sStart; s0 < sEnd; s0 += TS) {
        // stage K (64x64) and Vt (64x64): one short8 per thread per matrix
        {
            const int row = tid >> 3;
            const int c8 = (tid & 7) * 8;
            *(short8*)&K_lds[row][c8] =
                *(const short8*)((const short*)kb + (size_t)(s0 + row) * DQK + c8);
            *(short8*)&V_lds[row][c8] =
                *(const short8*)((const short*)vt + (size_t)row * TT + s0 + c8);
        }
        __syncthreads();

        const bool active = (s0 <= trow + 15);   // wave-uniform

        if (active) {
            // prefetch l (independent of LDS -> hides under MFMA)
            float lv[4][4];
            #pragma unroll
            for (int sub = 0; sub < 4; ++sub) {
                const int s_glob = s0 + sub * 16 + lo;
                #pragma unroll
                for (int r = 0; r < 4; ++r) {
                    const int tg = trow + hi * 4 + r;
                    lv[sub][r] = (s_glob <= tg) ? l[(size_t)tg * TT + s_glob] : 0.f;
                }
            }
            // QK^T -> *l -> bf16 -> S_lds
            #pragma unroll
            for (int sub = 0; sub < 4; ++sub) {
                f32x4 acc = (f32x4){0.f, 0.f, 0.f, 0.f};
                short8 b0 = *(short8*)&K_lds[sub * 16 + lo][hi * 8];
                short8 b1 = *(short8*)&K_lds[sub * 16 + lo][32 + hi * 8];
                acc = __builtin_amdgcn_mfma_f32_16x16x32_bf16(qf0, b0, acc, 0, 0, 0);
                acc = __builtin_amdgcn_mfma_f32_16x16x32_bf16(qf1, b1, acc, 0, 0, 0);
                #pragma unroll
                for (int r = 0; r < 4; ++r) {
                    float sv = acc[r] * lv[sub][r];
                    __hip_bfloat16 h = __float2bfloat16(sv);
                    S_lds[w][hi * 4 + r][sub * 16 + lo] = *(short*)&h;
                }
            }
        }
        __syncthreads();

        if (active) {
            // PV: O[16t x 64d] += S[16t x 64s] * V[64s x 64d]
            short8 a0 = *(short8*)&S_lds[w][lo][hi * 8];
            short8 a1 = *(short8*)&S_lds[w][lo][32 + hi * 8];
            #pragma unroll
            for (int ds = 0; ds < 4; ++ds) {
                short8 b0 = *(short8*)&V_lds[ds * 16 + lo][hi * 8];
                short8 b1 = *(short8*)&V_lds[ds * 16 + lo][32 + hi * 8];
                acc_o[ds] = __builtin_amdgcn_mfma_f32_16x16x32_bf16(a0, b0, acc_o[ds], 0, 0, 0);
                acc_o[ds] = __builtin_amdgcn_mfma_f32_16x16x32_bf16(a1, b1, acc_o[ds], 0, 0, 0);
            }
        }
        __syncthreads();
    }

    // epilogue: accumulate partials
    #pragma unroll
    for (int ds = 0; ds < 4; ++ds) {
        #pragma unroll
        for (int r = 0; r < 4; ++r) {
            const int tg = trow + hi * 4 + r;
            atomicAdd(&out[(size_t)tg * DQK + ds * 16 + lo], acc_o[ds][r]);
        }
    }
}

extern "C" void kernel_launch(void* const* d_in, const int* in_sizes, int n_in,
                              void* d_out, int out_size, void* d_ws, size_t ws_size,
                              hipStream_t stream) {
    const float* x  = (const float*)d_in[0];
    const float* Wq = (const float*)d_in[1];
    const float* Wk = (const float*)d_in[2];
    const float* Wv = (const float*)d_in[3];
    const float* l  = (const float*)d_in[4];
    float* out = (float*)d_out;

    __hip_bfloat16* qb = (__hip_bfloat16*)d_ws;
    __hip_bfloat16* kb = qb + (size_t)TT * DQK;
    __hip_bfloat16* vt = kb + (size_t)TT * DQK;

    zero_kernel<<<(out_size / 4 + 255) / 256, 256, 0, stream>>>(out, out_size / 4);
    proj_kernel<<<TT / 64, 256, 0, stream>>>(x, Wq, Wk, Wv, qb, kb, vt);
    attn_kernel<<<dim3(TT / TM, TT / SCHUNK), 512, 0, stream>>>(qb, kb, vt, l, out);
}

// Round 4
// 72.572 us; speedup vs baseline: 7.2257x; 1.0723x over previous
//
#include <hip/hip_runtime.h>
#include <hip/hip_bf16.h>

#define TT 8192
#define DIN 512
#define DQK 64

typedef __attribute__((ext_vector_type(8))) short short8;
typedef __attribute__((ext_vector_type(4))) float f32x4;

// ---------------- zero kernel ----------------
__global__ __launch_bounds__(256) void zero_kernel(float* __restrict__ out, int n4)
{
    int i = blockIdx.x * 256 + threadIdx.x;
    if (i < n4) ((f32x4*)out)[i] = (f32x4){0.f, 0.f, 0.f, 0.f};
}

// ---------------- Kernel 0: W [512][64] f32 -> WT bf16 [3][64][512] ----------------
__global__ __launch_bounds__(256) void wconv_kernel(
    const float* __restrict__ Wq, const float* __restrict__ Wk, const float* __restrict__ Wv,
    __hip_bfloat16* __restrict__ wtb)
{
    __shared__ float tile[64][65];
    const int m = blockIdx.y;
    const float* W = m == 0 ? Wq : (m == 1 ? Wk : Wv);
    const int k0 = blockIdx.x * 64;
    const int tid = threadIdx.x;

    {
        const int col4 = (tid & 15) * 4;
        #pragma unroll
        for (int it = 0; it < 4; ++it) {
            const int row = (tid >> 4) + it * 16;
            float4 v = *(const float4*)&W[(size_t)(k0 + row) * DQK + col4];
            tile[row][col4 + 0] = v.x; tile[row][col4 + 1] = v.y;
            tile[row][col4 + 2] = v.z; tile[row][col4 + 3] = v.w;
        }
    }
    __syncthreads();
    {
        const int d = tid >> 2;
        const int kc = (tid & 3) * 16;
        short tmp[16];
        #pragma unroll
        for (int j = 0; j < 16; ++j) {
            __hip_bfloat16 h = __float2bfloat16(tile[kc + j][d]);
            tmp[j] = *(short*)&h;
        }
        short* dst = (short*)wtb + ((size_t)m * 64 + d) * DIN + k0 + kc;
        *(short8*)dst       = *(short8*)&tmp[0];
        *(short8*)(dst + 8) = *(short8*)&tmp[8];
    }
}

// ---------------- Kernel 1: MFMA projections ----------------
#define PP 72

__global__ __launch_bounds__(256) void proj_kernel(
    const float* __restrict__ x,
    const __hip_bfloat16* __restrict__ wtb,
    __hip_bfloat16* __restrict__ qb, __hip_bfloat16* __restrict__ kb,
    __hip_bfloat16* __restrict__ vt)
{
    __shared__ short xb[64][PP];        // x tile [row][k]
    __shared__ short wb[3][64][PP];     // W^T tiles [m][col(d)][k]

    const int rowBase = blockIdx.x * 64;
    const int tid = threadIdx.x;
    const int lane = tid & 63;
    const int w = tid >> 6;
    const int lo = lane & 15, hi = lane >> 4;

    f32x4 acc[3][4];
    #pragma unroll
    for (int m = 0; m < 3; ++m)
        #pragma unroll
        for (int cf = 0; cf < 4; ++cf) acc[m][cf] = (f32x4){0.f, 0.f, 0.f, 0.f};

    for (int kk = 0; kk < DIN; kk += 64) {
        // stage x 64x64 -> bf16 (vectorized)
        {
            const int r = tid >> 2;
            const int c0 = (tid & 3) * 16;
            const float* xp = x + (size_t)(rowBase + r) * DIN + kk + c0;
            short tmp[16];
            #pragma unroll
            for (int j = 0; j < 16; j += 4) {
                float4 v = *(const float4*)(xp + j);
                __hip_bfloat16 h0 = __float2bfloat16(v.x);
                __hip_bfloat16 h1 = __float2bfloat16(v.y);
                __hip_bfloat16 h2 = __float2bfloat16(v.z);
                __hip_bfloat16 h3 = __float2bfloat16(v.w);
                tmp[j + 0] = *(short*)&h0; tmp[j + 1] = *(short*)&h1;
                tmp[j + 2] = *(short*)&h2; tmp[j + 3] = *(short*)&h3;
            }
            *(short8*)&xb[r][c0]     = *(short8*)&tmp[0];
            *(short8*)&xb[r][c0 + 8] = *(short8*)&tmp[8];
        }
        // stage W^T (already bf16, vector copy)
        {
            const int d = tid >> 2;
            const int kc = (tid & 3) * 16;
            #pragma unroll
            for (int m = 0; m < 3; ++m) {
                const short* src = (const short*)wtb + ((size_t)m * 64 + d) * DIN + kk + kc;
                *(short8*)&wb[m][d][kc]     = *(const short8*)src;
                *(short8*)&wb[m][d][kc + 8] = *(const short8*)(src + 8);
            }
        }
        __syncthreads();

        short8 a0 = *(short8*)&xb[w * 16 + lo][hi * 8];
        short8 a1 = *(short8*)&xb[w * 16 + lo][32 + hi * 8];
        #pragma unroll
        for (int m = 0; m < 3; ++m) {
            #pragma unroll
            for (int cf = 0; cf < 4; ++cf) {
                short8 b0 = *(short8*)&wb[m][cf * 16 + lo][hi * 8];
                short8 b1 = *(short8*)&wb[m][cf * 16 + lo][32 + hi * 8];
                acc[m][cf] = __builtin_amdgcn_mfma_f32_16x16x32_bf16(a0, b0, acc[m][cf], 0, 0, 0);
                acc[m][cf] = __builtin_amdgcn_mfma_f32_16x16x32_bf16(a1, b1, acc[m][cf], 0, 0, 0);
            }
        }
        __syncthreads();
    }

    #pragma unroll
    for (int cf = 0; cf < 4; ++cf) {
        #pragma unroll
        for (int r = 0; r < 4; ++r) {
            const int tg = rowBase + w * 16 + hi * 4 + r;
            const int d  = cf * 16 + lo;
            __hip_bfloat16 hq = __float2bfloat16(acc[0][cf][r]);
            __hip_bfloat16 hk = __float2bfloat16(acc[1][cf][r]);
            __hip_bfloat16 hv = __float2bfloat16(acc[2][cf][r]);
            qb[(size_t)tg * DQK + d] = hq;
            kb[(size_t)tg * DQK + d] = hk;
            vt[(size_t)d * TT + tg]  = hv;
        }
    }
}

// ---------------- Kernel 2: MFMA triangular core ----------------
#define TM 128       // t rows per block (8 waves x 16)
#define TS 64        // s per step
#define SCHUNK 256   // s range per block (grid.y)
#define LP 72        // padded LDS row stride in shorts (144 B)

__global__ __launch_bounds__(512) void attn_kernel(
    const __hip_bfloat16* __restrict__ qb,
    const __hip_bfloat16* __restrict__ kb,
    const __hip_bfloat16* __restrict__ vt,
    const float* __restrict__ l,
    float* __restrict__ out)
{
    __shared__ short K_lds[TS][LP];      // K[s][k]
    __shared__ short V_lds[DQK][LP];     // Vt[d][s_local]
    __shared__ short S_lds[8][16][LP];   // per-wave (wave-private) S[t_loc][s_local]

    const int t0 = blockIdx.x * TM;
    const int sStart = blockIdx.y * SCHUNK;
    if (sStart >= t0 + TM) return;
    const int sEnd = min(sStart + SCHUNK, t0 + TM);

    const int tid = threadIdx.x;
    const int lane = tid & 63;
    const int w = tid >> 6;
    const int lo = lane & 15, hi = lane >> 4;
    const int trow = t0 + w * 16;

    short8 qf0, qf1;
    {
        const short* qp = (const short*)qb + (size_t)(trow + lo) * DQK;
        qf0 = *(const short8*)(qp + hi * 8);
        qf1 = *(const short8*)(qp + 32 + hi * 8);
    }

    f32x4 acc_o[4];
    #pragma unroll
    for (int i = 0; i < 4; ++i) acc_o[i] = (f32x4){0.f, 0.f, 0.f, 0.f};

    // l register double-buffer: lvC = current step, lvN = next step (prefetch)
    float lvC[4][4];
    float lvN[4][4] = {{0.f}};
    {
        #pragma unroll
        for (int sub = 0; sub < 4; ++sub) {
            const int s_glob = sStart + sub * 16 + lo;
            #pragma unroll
            for (int r = 0; r < 4; ++r) {
                const int tg = trow + hi * 4 + r;
                lvC[sub][r] = (s_glob <= tg) ? l[(size_t)tg * TT + s_glob] : 0.f;
            }
        }
    }

    for (int s0 = sStart; s0 < sEnd; s0 += TS) {
        // stage K (64x64) and Vt (64x64)
        {
            const int row = tid >> 3;
            const int c8 = (tid & 7) * 8;
            *(short8*)&K_lds[row][c8] =
                *(const short8*)((const short*)kb + (size_t)(s0 + row) * DQK + c8);
            *(short8*)&V_lds[row][c8] =
                *(const short8*)((const short*)vt + (size_t)row * TT + s0 + c8);
        }
        __syncthreads();

        const bool active = (s0 <= trow + 15);
        const int sN = s0 + TS;
        const bool act_next = (sN < sEnd) && (sN <= trow + 15);

        // prefetch next step's l slice (hides HBM latency under MFMA)
        if (act_next) {
            #pragma unroll
            for (int sub = 0; sub < 4; ++sub) {
                const int s_glob = sN + sub * 16 + lo;
                #pragma unroll
                for (int r = 0; r < 4; ++r) {
                    const int tg = trow + hi * 4 + r;
                    lvN[sub][r] = (s_glob <= tg) ? l[(size_t)tg * TT + s_glob] : 0.f;
                }
            }
        }

        if (active) {
            // QK^T -> *l -> bf16 -> S_lds (wave-private: no barrier needed before PV)
            #pragma unroll
            for (int sub = 0; sub < 4; ++sub) {
                f32x4 acc = (f32x4){0.f, 0.f, 0.f, 0.f};
                short8 b0 = *(short8*)&K_lds[sub * 16 + lo][hi * 8];
                short8 b1 = *(short8*)&K_lds[sub * 16 + lo][32 + hi * 8];
                acc = __builtin_amdgcn_mfma_f32_16x16x32_bf16(qf0, b0, acc, 0, 0, 0);
                acc = __builtin_amdgcn_mfma_f32_16x16x32_bf16(qf1, b1, acc, 0, 0, 0);
                #pragma unroll
                for (int r = 0; r < 4; ++r) {
                    float sv = acc[r] * lvC[sub][r];
                    __hip_bfloat16 h = __float2bfloat16(sv);
                    S_lds[w][hi * 4 + r][sub * 16 + lo] = *(short*)&h;
                }
            }
            // PV: O[16t x 64d] += S[16t x 64s] * V[64s x 64d]
            short8 a0 = *(short8*)&S_lds[w][lo][hi * 8];
            short8 a1 = *(short8*)&S_lds[w][lo][32 + hi * 8];
            #pragma unroll
            for (int ds = 0; ds < 4; ++ds) {
                short8 b0 = *(short8*)&V_lds[ds * 16 + lo][hi * 8];
                short8 b1 = *(short8*)&V_lds[ds * 16 + lo][32 + hi * 8];
                acc_o[ds] = __builtin_amdgcn_mfma_f32_16x16x32_bf16(a0, b0, acc_o[ds], 0, 0, 0);
                acc_o[ds] = __builtin_amdgcn_mfma_f32_16x16x32_bf16(a1, b1, acc_o[ds], 0, 0, 0);
            }
        }
        __syncthreads();

        #pragma unroll
        for (int sub = 0; sub < 4; ++sub)
            #pragma unroll
            for (int r = 0; r < 4; ++r)
                lvC[sub][r] = lvN[sub][r];
    }

    #pragma unroll
    for (int ds = 0; ds < 4; ++ds) {
        #pragma unroll
        for (int r = 0; r < 4; ++r) {
            const int tg = trow + hi * 4 + r;
            atomicAdd(&out[(size_t)tg * DQK + ds * 16 + lo], acc_o[ds][r]);
        }
    }
}

extern "C" void kernel_launch(void* const* d_in, const int* in_sizes, int n_in,
                              void* d_out, int out_size, void* d_ws, size_t ws_size,
                              hipStream_t stream) {
    const float* x  = (const float*)d_in[0];
    const float* Wq = (const float*)d_in[1];
    const float* Wk = (const float*)d_in[2];
    const float* Wv = (const float*)d_in[3];
    const float* l  = (const float*)d_in[4];
    float* out = (float*)d_out;

    __hip_bfloat16* qb  = (__hip_bfloat16*)d_ws;
    __hip_bfloat16* kb  = qb + (size_t)TT * DQK;
    __hip_bfloat16* vt  = kb + (size_t)TT * DQK;
    __hip_bfloat16* wtb = vt + (size_t)TT * DQK;   // [3][64][512]

    zero_kernel<<<(out_size / 4 + 255) / 256, 256, 0, stream>>>(out, out_size / 4);
    wconv_kernel<<<dim3(DIN / 64, 3), 256, 0, stream>>>(Wq, Wk, Wv, wtb);
    proj_kernel<<<TT / 64, 256, 0, stream>>>(x, wtb, qb, kb, vt);
    attn_kernel<<<dim3(TT / TM, TT / SCHUNK), 512, 0, stream>>>(qb, kb, vt, l, out);
}